// Round 1
// baseline (416.099 us; speedup 1.0000x reference)
//
#include <hip/hip_runtime.h>

// TV-L1 optical flow, B=4, 512x512, 20 iters — temporal blocking (ghost zones)
// R6: register diet vs R5. launch_bounds(1024,1) caps VGPRs at 128 (4 waves/
// SIMD); R5's per-slot mirrors (~105 array VGPRs + temps) sat at/over the cap.
// Changes:
//   - gofs[] dropped: gl recomputed as (li<<9)+lj+cb (2 VALU) where needed.
//   - rpa/rpb persistent mirrors dropped: main loop reads spa[idx]/spb[idx]
//     from LDS (they are pass1->pass3 temps tpa/tpb only, dead in main loop).
//   - rth[] eliminated: |rho|<th  <=>  |rho*rnv|<tl  (nm>0), so the soft-
//     threshold select collapses to d = clamp(rho*rnv, -tl, tl) = v_med3.
//     Boundary is continuous, so the rcp-induced branch-point shift is exact.
// Main-loop array VGPRs: lis/ljs 14 + ruv 14 + rgx/rgy/rrc/rnv 28 = 56.
//   LDS: su=(u1,u2), spa=(p11,p21), spb=(p12,p22), 3 x 6400 x 8B = 153.6 KB.
// Halo L=6/R=10 (80x80 region per 64x64 tile). Zero-padding reproduced by
// forcing u=p=0 on out-of-image pixels. Last kernel skips the dead 20th
// p-update and fuses the 3x3 avgpool.

#define HH 512
#define WW 512
#define BB 4
constexpr int HW   = HH * WW;
constexpr int NTOT = BB * HW;
constexpr float EPS = 1e-8f;

#define T 64          // output tile edge
#define HALO_L 6      // left/top halo
#define REG 80        // region edge = 64 + 6 + 10
#define NPX (REG * REG)   // 6400
#define TPB 1024
#define SLOTS 7       // ceil(6400/1024)
#define NBLK 256      // 4 images x 8x8 tiles
#define XR 82         // x1 staging edge (region + 1-ring for 3x3 gradient)
#define XN (XR * XR)  // 6724 <= 12800 floats available in spa

// phase: 0 = first (u,p zero-init, write back), 1 = middle (load, write
// back), 2 = last (load, 5 u-phases + 4 p-phases, fused avgpool -> out).
__global__ __launch_bounds__(TPB, 1) void k_fused(
    const float* __restrict__ x,
    float2* __restrict__ ug, float4* __restrict__ pg,
    const float* __restrict__ lam_p, const float* __restrict__ tau_p,
    const float* __restrict__ theta_p,
    const float* __restrict__ wxp, const float* __restrict__ wyp,
    float* __restrict__ out, int phase)
{
    __shared__ float2 su[NPX];    // (u1,u2)
    __shared__ float2 spa[NPX];   // (p11,p21); doubles as x1 staging buffer
    __shared__ float2 spb[NPX];   // (p12,p22)   -> 153.6 KB total

    const int tid  = threadIdx.x;
    const int blk  = blockIdx.x;
    const int bimg = blk >> 6;
    const int t    = blk & 63;
    const int gi0  = (t >> 3) * T;
    const int gj0  = (t & 7) * T;

    const float lam = lam_p[0], theta = theta_p[0];
    const float r   = tau_p[0] / theta;
    const float tl  = theta * lam;
    const float wx0 = wxp[0], wx1 = wxp[1], wx2 = wxp[2];
    const float wy0 = wyp[0], wy1 = wyp[1], wy2 = wyp[2];

    const int gbase = bimg * HW;
    const int cb    = (gi0 - HALO_L) * WW + (gj0 - HALO_L);  // gl=(li<<9)+lj+cb
    const float* x0p = x + (size_t)bimg * 2 * HW;
    const float* x1p = x0p + HW;

    int  lis[SLOTS], ljs[SLOTS];
    bool inb[SLOTS];
    float2 ruv[SLOTS];            // own-pixel u mirror (hot in both phases)
    float2 tpa[SLOTS], tpb[SLOTS];  // pass1->pass3 p-state temps ONLY
    float  x0v[SLOTS];            // pass1->pass2 temp ONLY

    // ---- pass 1: stage x1 into spa-as-float; precompute per-slot indices;
    //      issue state loads early (consumed in pass 3, overlap statics) ----
    #pragma unroll
    for (int s = 0; s < SLOTS; ++s) {
        int idx = tid + s * TPB;
        if (idx < XN) {
            int li = idx / XR, lj = idx - li * XR;
            int gi = gi0 + li - (HALO_L + 1), gj = gj0 + lj - (HALO_L + 1);
            bool in = ((unsigned)gi < HH) & ((unsigned)gj < WW);
            ((float*)spa)[idx] = in ? x1p[gi * WW + gj] : 0.f;
        }
        if (idx < NPX) {
            int li = idx / REG, lj = idx - li * REG;
            lis[s] = li; ljs[s] = lj;
            int gi = gi0 + li - HALO_L, gj = gj0 + lj - HALO_L;
            bool in = ((unsigned)gi < HH) & ((unsigned)gj < WW);
            inb[s] = in;
            int gl = (li << 9) + lj + cb;     // == gi*WW+gj, valid only when in
            float2 uv = make_float2(0.f, 0.f);
            float4 p4 = make_float4(0.f, 0.f, 0.f, 0.f);
            float xv = 0.f;
            if (in) {
                xv = x0p[gl];
                if (phase != 0) {
                    uv = ug[gbase + gl];
                    p4 = pg[gbase + gl];
                }
            }
            x0v[s] = xv;
            ruv[s] = uv;
            tpa[s] = make_float2(p4.x, p4.y);
            tpb[s] = make_float2(p4.z, p4.w);
        }
    }
    __syncthreads();

    // ---- pass 2: statics (gx,gy,rc,1/nm) from staged x1 -------------------
    float rgx[SLOTS], rgy[SLOTS], rrc[SLOTS], rnv[SLOTS];
    const float* stg = (const float*)spa;
    #pragma unroll
    for (int s = 0; s < SLOTS; ++s) {
        int idx = tid + s * TPB;
        if (idx < NPX) {
            int sc = (lis[s] + 1) * XR + (ljs[s] + 1);
            float a00 = stg[sc - XR - 1], a01 = stg[sc - XR], a02 = stg[sc - XR + 1];
            float a10 = stg[sc - 1],      a11 = stg[sc],      a12 = stg[sc + 1];
            float a20 = stg[sc + XR - 1], a21 = stg[sc + XR], a22 = stg[sc + XR + 1];
            const float c6 = 1.f / 6.f;
            float gxv = c6 * (-a00 + a02 - 2.f * a10 + 2.f * a12 - a20 + a22);
            float gyv = c6 * (-a00 - 2.f * a01 - a02 + a20 + 2.f * a21 + a22);
            float nm  = gxv * gxv + gyv * gyv + EPS;
            rgx[s] = gxv; rgy[s] = gyv;
            rrc[s] = a11 - x0v[s];           // zero-padded conv semantics held
            rnv[s] = __builtin_amdgcn_rcpf(nm);
        }
    }
    __syncthreads();

    // ---- pass 3: fill LDS state (overwrites staging) ----------------------
    #pragma unroll
    for (int s = 0; s < SLOTS; ++s) {
        int idx = tid + s * TPB;
        if (idx < NPX) {
            su[idx]  = ruv[s];
            spa[idx] = tpa[s];
            spb[idx] = tpb[s];
        }
    }
    __syncthreads();

    // ---- 5 fused iterations ----------------------------------------------
    for (int k = 1; k <= 5; ++k) {
        // u-phase over li,lj in [k, REG-2k]  (valid cone of u^k)
        const int lo = k, hi_u = REG - 2 * k;
        #pragma unroll
        for (int s = 0; s < SLOTS; ++s) {
            int idx = tid + s * TPB;
            if (idx >= NPX) continue;
            int li = lis[s], lj = ljs[s];
            if (li < lo || li > hi_u || lj < lo || lj > hi_u) continue;
            float2 uv = ruv[s];
            float rho = rrc[s] + rgx[s] * uv.x + rgy[s] * uv.y;
            // |rho| < th  <=>  |rho*rnv| < tl  (nm>0); boundary continuous,
            // so d = clamp(rho*rnv, -tl, tl) == reference select (v_med3).
            float tt = rho * rnv[s];
            float d  = fminf(fmaxf(tt, -tl), tl);
            float v1 = uv.x - d * rgx[s];
            float v2 = uv.y - d * rgy[s];
            float2 pal = spa[idx - 1],   pac = spa[idx],   par = spa[idx + 1];
            float2 pbt = spb[idx - REG], pbc = spb[idx],   pbb = spb[idx + REG];
            float div1 = wx0 * pal.x + wx1 * pac.x + wx2 * par.x
                       + wy0 * pbt.x + wy1 * pbc.x + wy2 * pbb.x;
            float div2 = wx0 * pal.y + wx1 * pac.y + wx2 * par.y
                       + wy0 * pbt.y + wy1 * pbc.y + wy2 * pbb.y;
            float nu1 = v1 + theta * div1;
            float nu2 = v2 + theta * div2;
            if (!inb[s]) { nu1 = 0.f; nu2 = 0.f; }   // zero-padding semantics
            float2 nuv = make_float2(nu1, nu2);
            ruv[s] = nuv; su[idx] = nuv;
        }
        __syncthreads();
        if (phase == 2 && k == 5) break;   // 20th p-update is dead code

        // p-phase over li,lj in [k, REG-1-2k]  (valid cone of p^k)
        const int hi_p = REG - 1 - 2 * k;
        #pragma unroll
        for (int s = 0; s < SLOTS; ++s) {
            int idx = tid + s * TPB;
            if (idx >= NPX) continue;
            int li = lis[s], lj = ljs[s];
            if (li < lo || li > hi_p || lj < lo || lj > hi_p) continue;
            float2 uc = ruv[s];
            float2 uR = su[idx + 1];
            float2 uB = su[idx + REG];
            float gu1x = uR.x - uc.x, gu1y = uB.x - uc.x;
            float gu2x = uR.y - uc.y, gu2y = uB.y - uc.y;
            float2 pac = spa[idx], pbc = spb[idx];
            float d1 = 1.f + r * (fabsf(gu1x) + fabsf(gu1y));
            float id1 = __builtin_amdgcn_rcpf(d1);
            float np11 = (pac.x + r * gu1x) * id1;
            float np12 = (pbc.x + r * gu1y) * id1;
            float d2 = 1.f + r * (fabsf(gu2x) + fabsf(gu2y));
            float id2 = __builtin_amdgcn_rcpf(d2);
            float np21 = (pac.y + r * gu2x) * id2;
            float np22 = (pbc.y + r * gu2y) * id2;
            if (!inb[s]) { np11 = 0.f; np12 = 0.f; np21 = 0.f; np22 = 0.f; }
            spa[idx] = make_float2(np11, np21);
            spb[idx] = make_float2(np12, np22);
        }
        __syncthreads();
    }

    // ---- epilogue ---------------------------------------------------------
    if (phase != 2) {
        // write back interior [0,63]^2 (li,lj in [6,69])
        #pragma unroll
        for (int s = 0; s < SLOTS; ++s) {
            int idx = tid + s * TPB;
            if (idx >= NPX) continue;
            int li = lis[s], lj = ljs[s];
            if (li < HALO_L || li >= HALO_L + T || lj < HALO_L || lj >= HALO_L + T) continue;
            int gl = (li << 9) + lj + cb;
            ug[gbase + gl] = ruv[s];
            float2 pa = spa[idx], pb = spb[idx];
            pg[gbase + gl] = make_float4(pa.x, pa.y, pb.x, pb.y);
        }
    } else {
        // fused avgpool(3,1,1, /9 always); u^5 valid on [-1,64] — exact fit
        const float inv9 = 1.f / 9.f;
        #pragma unroll
        for (int s = 0; s < SLOTS; ++s) {
            int idx = tid + s * TPB;
            if (idx >= NPX) continue;
            int li = lis[s], lj = ljs[s];
            if (li < HALO_L || li >= HALO_L + T || lj < HALO_L || lj >= HALO_L + T) continue;
            float2 a0 = su[idx - REG - 1], a1 = su[idx - REG], a2 = su[idx - REG + 1];
            float2 b0 = su[idx - 1],       b1 = su[idx],       b2 = su[idx + 1];
            float2 c0 = su[idx + REG - 1], c1 = su[idx + REG], c2 = su[idx + REG + 1];
            float s1 = a0.x + a1.x + a2.x + b0.x + b1.x + b2.x + c0.x + c1.x + c2.x;
            float s2 = a0.y + a1.y + a2.y + b0.y + b1.y + b2.y + c0.y + c1.y + c2.y;
            int gl = (li << 9) + lj + cb;
            out[(size_t)bimg * 2 * HW + gl]      = s1 * inv9;
            out[(size_t)bimg * 2 * HW + HW + gl] = s2 * inv9;
        }
    }
}

// --------------------------------------------------------------- launch ---
extern "C" void kernel_launch(void* const* d_in, const int* in_sizes, int n_in,
                              void* d_out, int out_size, void* d_ws, size_t ws_size,
                              hipStream_t stream) {
    const float* x     = (const float*)d_in[0];
    const float* lam   = (const float*)d_in[1];
    const float* tau   = (const float*)d_in[2];
    const float* theta = (const float*)d_in[3];
    const float* wx    = (const float*)d_in[4];
    const float* wy    = (const float*)d_in[5];
    float* out = (float*)d_out;

    float*  ws = (float*)d_ws;
    float2* ug = (float2*)ws;                         // 8 MB
    float4* pg = (float4*)(ws + (size_t)2 * NTOT);    // 16 MB

    for (int c = 0; c < 4; ++c) {
        int phase = (c == 0) ? 0 : (c == 3) ? 2 : 1;
        k_fused<<<dim3(NBLK), dim3(TPB), 0, stream>>>(
            x, ug, pg, lam, tau, theta, wx, wy, out, phase);
    }
}